// Round 1
// baseline (133.182 us; speedup 1.0000x reference)
//
#include <hip/hip_runtime.h>
#include <cstdint>

#define DD 24
#define AA 13824          // 24*24*24
#define NF4 3456          // AA/4
#define TOPK 60
#define NMS_TOPK 20
#define THRESH 0.15f
#define NMS_THR 0.05f
#define NBINS 4096
#define BUFCAP 2048

__device__ __forceinline__ unsigned skey(float f) {
    unsigned u = __float_as_uint(f);
    return (u & 0x80000000u) ? ~u : (u | 0x80000000u);
}

__global__ __launch_bounds__(256) void detpost(
    const float* __restrict__ cls,
    const float* __restrict__ shp,
    const float* __restrict__ off,
    float* __restrict__ out)
{
    __shared__ int   s_hist[NBINS];
    __shared__ int   s_S[257];
    __shared__ int   s_wsum[4];
    __shared__ int   s_seg;
    __shared__ int   s_bt;
    __shared__ int   s_cnt;
    __shared__ float s_bufv[BUFCAP];
    __shared__ int   s_bufi[BUFCAP];
    __shared__ float s_topv[TOPK];
    __shared__ int   s_topi[TOPK];

    const int b   = blockIdx.x;
    const int tid = threadIdx.x;

    for (int i = tid; i < NBINS; i += 256) s_hist[i] = 0;
    if (tid == 0) { s_cnt = 0; s_seg = 0; s_S[256] = 0; }
    __syncthreads();

    // ---- Pass 1: histogram of sortable keys (top 12 bits) ----
    const float4* cls4 = (const float4*)(cls + (size_t)b * AA);
    for (int k = tid; k < NF4; k += 256) {
        float4 v = cls4[k];
        atomicAdd(&s_hist[skey(v.x) >> 20], 1);
        atomicAdd(&s_hist[skey(v.y) >> 20], 1);
        atomicAdd(&s_hist[skey(v.z) >> 20], 1);
        atomicAdd(&s_hist[skey(v.w) >> 20], 1);
    }
    __syncthreads();

    // ---- Find pivot bin: smallest bin bt with count(key_bin >= bt) >= TOPK ----
    int part = 0;
    #pragma unroll
    for (int i = 0; i < 16; ++i) part += s_hist[tid * 16 + i];

    const int lane = tid & 63, wv = tid >> 6;
    int x = part;
    #pragma unroll
    for (int d2 = 1; d2 < 64; d2 <<= 1) {
        int y = __shfl_up(x, d2, 64);
        if (lane >= d2) x += y;
    }
    if (lane == 63) s_wsum[wv] = x;
    __syncthreads();
    int offp = 0, tot = 0;
    #pragma unroll
    for (int wq = 0; wq < 4; ++wq) {
        int s = s_wsum[wq];
        tot += s;
        if (wq < wv) offp += s;
    }
    const int Pincl = x + offp;
    const int S = tot - Pincl + part;   // suffix sum over segments >= tid
    s_S[tid] = S;
    if (S >= TOPK) atomicMax(&s_seg, tid);
    __syncthreads();

    if (tid == 0) {
        const int seg = s_seg;
        int acc = s_S[seg + 1];         // count strictly above this segment (< TOPK)
        int bt  = seg * 16;
        for (int i = 15; i >= 0; --i) {
            int c = s_hist[seg * 16 + i];
            if (acc + c >= TOPK) { bt = seg * 16 + i; break; }
            acc += c;
        }
        s_bt = bt;
    }
    __syncthreads();
    const unsigned bt = (unsigned)s_bt;

    // ---- Pass 2 (L2-hot): collect candidates with bin >= bt ----
    const float* clsb = cls + (size_t)b * AA;
    for (int e = tid; e < AA; e += 256) {
        float v = clsb[e];
        if ((skey(v) >> 20) >= bt) {
            int pos = atomicAdd(&s_cnt, 1);
            if (pos < BUFCAP) { s_bufv[pos] = v; s_bufi[pos] = e; }
        }
    }
    __syncthreads();
    int C = s_cnt; if (C > BUFCAP) C = BUFCAP;

    // ---- Exact top-60 by rank counting (desc value, tie: lower index first) ----
    for (int j = tid; j < C; j += 256) {
        const float vj = s_bufv[j];
        const int   ij = s_bufi[j];
        int r = 0;
        for (int k = 0; k < C; ++k) {
            const float vk = s_bufv[k];
            const int   ik = s_bufi[k];
            r += (int)((vk > vj) || (vk == vj && ik < ij));
        }
        if (r < TOPK) { s_topv[r] = vj; s_topi[r] = ij; }
    }
    __syncthreads();

    // ---- NMS + output, wave 0 only ----
    if (tid < 64) {
        const int j = tid;
        const bool live = (j < TOPK);
        float score = 0.f;
        float cz = 0, cy = 0, cx = 0, ez = 0, ey = 0, ex = 0;
        if (live) {
            const float v = s_topv[j];
            const int   a = s_topi[j];
            score = 1.0f / (1.0f + expf(-v));
            const int z = a / (DD * DD);
            const int y = (a / DD) % DD;
            const int xg = a % DD;
            const size_t base3 = (size_t)b * 3 * AA;
            const float o0 = off[base3 + 0 * AA + a];
            const float o1 = off[base3 + 1 * AA + a];
            const float o2 = off[base3 + 2 * AA + a];
            const float s0 = shp[base3 + 0 * AA + a];
            const float s1 = shp[base3 + 1 * AA + a];
            const float s2 = shp[base3 + 2 * AA + a];
            cz = ((float)z  + o0) * 4.0f;
            cy = ((float)y  + o1) * 4.0f;
            cx = ((float)xg + o2) * 4.0f;
            ez = 2.0f * s0; ey = 2.0f * s1; ex = 2.0f * s2;
        }
        // mirror reference fp op order exactly
        const float loz = cz - ez * 0.5f, hiz = cz + ez * 0.5f;
        const float loy = cy - ey * 0.5f, hiy = cy + ey * 0.5f;
        const float lox = cx - ex * 0.5f, hix = cx + ex * 0.5f;
        const float vol = (ez * ey) * ex;

        const bool valid = live && (score > THRESH);
        const unsigned long long vmask = __ballot(valid);
        const int rank = __popcll(vmask & ((1ull << j) - 1ull));
        const bool cand = valid && (rank < NMS_TOPK);
        const unsigned long long candmask = __ballot(cand);

        unsigned long long suppmask = 0ull;
        unsigned long long keptmask = 0ull;
        bool suppj = false;
        for (int i = 0; i < TOPK; ++i) {
            const bool keep_i = ((candmask >> i) & 1ull) && !((suppmask >> i) & 1ull);
            if (keep_i) {   // wave-uniform branch
                keptmask |= (1ull << i);
                const float ilz = __shfl(loz, i), ihz = __shfl(hiz, i);
                const float ily = __shfl(loy, i), ihy = __shfl(hiy, i);
                const float ilx = __shfl(lox, i), ihx = __shfl(hix, i);
                const float ivol = __shfl(vol, i);
                const float tz = fmaxf(fminf(ihz, hiz) - fmaxf(ilz, loz), 0.0f);
                const float ty = fmaxf(fminf(ihy, hiy) - fmaxf(ily, loy), 0.0f);
                const float tx = fmaxf(fminf(ihx, hix) - fmaxf(ilx, lox), 0.0f);
                const float inter = (tz * ty) * tx;
                const float uni = (ivol + vol) - inter;
                const float iou = inter / fmaxf(uni, 1e-8f);
                suppj = suppj || (iou > NMS_THR && j != i);
                suppmask = __ballot(suppj);
            }
        }
        const int K = __popcll(keptmask);
        float* ob = out + (size_t)b * (TOPK * 8);
        const bool keptj = live && ((keptmask >> j) & 1ull);
        if (keptj) {
            const int r = __popcll(keptmask & ((1ull << j) - 1ull));
            float* row = ob + r * 8;
            row[0] = 1.0f;  row[1] = score;
            row[2] = cz;    row[3] = cy;   row[4] = cx;
            row[5] = ez;    row[6] = ey;   row[7] = ex;
        }
        for (int r = K + j; r < TOPK; r += 64) {
            float* row = ob + r * 8;
            #pragma unroll
            for (int q = 0; q < 8; ++q) row[q] = -1.0f;
        }
    }
}

extern "C" void kernel_launch(void* const* d_in, const int* in_sizes, int n_in,
                              void* d_out, int out_size, void* d_ws, size_t ws_size,
                              hipStream_t stream) {
    (void)n_in; (void)out_size; (void)d_ws; (void)ws_size;
    const float* cls = (const float*)d_in[0];
    const float* shp = (const float*)d_in[1];
    const float* off = (const float*)d_in[2];
    float* out = (float*)d_out;
    const int B = in_sizes[0] / AA;   // 256
    detpost<<<B, 256, 0, stream>>>(cls, shp, off, out);
}

// Round 2
// 120.153 us; speedup vs baseline: 1.1084x; 1.1084x over previous
//
#include <hip/hip_runtime.h>
#include <cstdint>

#define DD 24
#define AA 13824          // 24*24*24
#define NF4 3456          // AA/4
#define BLOCK 1024
#define TOPK 60
#define NMS_TOPK 20
#define THRESH 0.15f
#define NMS_THR 0.05f
#define NBINS 4096
#define BUFCAP 2048

__device__ __forceinline__ unsigned skey(float f) {
    unsigned u = __float_as_uint(f);
    return (u & 0x80000000u) ? ~u : (u | 0x80000000u);
}

__global__ __launch_bounds__(BLOCK, 4) void detpost(
    const float* __restrict__ cls,
    const float* __restrict__ shp,
    const float* __restrict__ off,
    float* __restrict__ out)
{
    __shared__ int      s_hist[NBINS];
    __shared__ int      s_S[257];
    __shared__ int      s_wsum[4];
    __shared__ int      s_seg;
    __shared__ int      s_bt;
    __shared__ int      s_cnt;
    __shared__ float    s_bufv[BUFCAP];
    __shared__ int      s_bufi[BUFCAP];
    __shared__ float    s_topv[TOPK];
    __shared__ int      s_topi[TOPK];
    __shared__ float    s_lo[3][TOPK], s_hi[3][TOPK], s_vol[TOPK];
    __shared__ float    s_det[TOPK][8];      // 1, score, cz, cy, cx, ez, ey, ex
    __shared__ unsigned s_mLo[TOPK], s_mHi[TOPK];
    __shared__ unsigned long long s_candmask, s_keptmask;

    const int b   = blockIdx.x;
    const int tid = threadIdx.x;

    for (int i = tid; i < NBINS; i += BLOCK) s_hist[i] = 0;
    if (tid < TOPK) { s_mLo[tid] = 0u; s_mHi[tid] = 0u; }
    if (tid == 0) { s_cnt = 0; s_seg = 0; s_S[256] = 0; }
    __syncthreads();

    // ---- Pass 1: load cls into registers + histogram of top-12-bit sortable keys
    const float4* cls4 = (const float4*)(cls + (size_t)b * AA);
    const bool has3 = (tid + 3072) < NF4;    // NF4 = 3456: threads 0..383
    float4 r0 = cls4[tid];
    float4 r1 = cls4[tid + 1024];
    float4 r2 = cls4[tid + 2048];
    float4 r3 = has3 ? cls4[tid + 3072] : make_float4(0.f, 0.f, 0.f, 0.f);

    atomicAdd(&s_hist[skey(r0.x) >> 20], 1);
    atomicAdd(&s_hist[skey(r0.y) >> 20], 1);
    atomicAdd(&s_hist[skey(r0.z) >> 20], 1);
    atomicAdd(&s_hist[skey(r0.w) >> 20], 1);
    atomicAdd(&s_hist[skey(r1.x) >> 20], 1);
    atomicAdd(&s_hist[skey(r1.y) >> 20], 1);
    atomicAdd(&s_hist[skey(r1.z) >> 20], 1);
    atomicAdd(&s_hist[skey(r1.w) >> 20], 1);
    atomicAdd(&s_hist[skey(r2.x) >> 20], 1);
    atomicAdd(&s_hist[skey(r2.y) >> 20], 1);
    atomicAdd(&s_hist[skey(r2.z) >> 20], 1);
    atomicAdd(&s_hist[skey(r2.w) >> 20], 1);
    if (has3) {
        atomicAdd(&s_hist[skey(r3.x) >> 20], 1);
        atomicAdd(&s_hist[skey(r3.y) >> 20], 1);
        atomicAdd(&s_hist[skey(r3.z) >> 20], 1);
        atomicAdd(&s_hist[skey(r3.w) >> 20], 1);
    }
    __syncthreads();

    // ---- Find pivot bin bt: smallest bin with count(bin >= bt) >= TOPK (waves 0-3)
    if (tid < 256) {
        int part = 0;
        #pragma unroll
        for (int i = 0; i < 16; ++i) part += s_hist[tid * 16 + i];
        const int lane = tid & 63, wv = tid >> 6;
        int x = part;
        #pragma unroll
        for (int d2 = 1; d2 < 64; d2 <<= 1) {
            int y = __shfl_up(x, d2, 64);
            if (lane >= d2) x += y;
        }
        if (lane == 63) s_wsum[wv] = x;
        s_S[tid] = part;            // stash part; finish after sync
        s_topi[0] = 0;              // dummy to keep compiler honest (overwritten later)
        // store x temporarily in s_bufi region? no — recompute below cheaply
        s_bufv[tid] = __int_as_float(x);   // stash inclusive wave-scan
    }
    __syncthreads();
    if (tid < 256) {
        const int wv = tid >> 6;
        const int part = s_S[tid];
        const int x = __float_as_int(s_bufv[tid]);
        int offp = 0, tot = 0;
        #pragma unroll
        for (int wq = 0; wq < 4; ++wq) {
            int s = s_wsum[wq];
            tot += s;
            if (wq < wv) offp += s;
        }
        const int Pincl = x + offp;
        const int S = tot - Pincl + part;   // suffix sum over segments >= tid
        s_S[tid] = S;
        if (S >= TOPK) atomicMax(&s_seg, tid);
    }
    __syncthreads();
    if (tid == 0) {
        const int seg = s_seg;
        int acc = (seg < 255) ? s_S[seg + 1] : 0;
        int bt = seg * 16;
        for (int i = 15; i >= 0; --i) {
            int c = s_hist[seg * 16 + i];
            if (acc + c >= TOPK) { bt = seg * 16 + i; break; }
            acc += c;
        }
        s_bt = bt;
    }
    __syncthreads();
    const unsigned bt = (unsigned)s_bt;

    // ---- Pass 2: collect candidates from registers ----
    {
        const int b0 = 4 * tid, b1 = 4 * (tid + 1024), b2 = 4 * (tid + 2048), b3 = 4 * (tid + 3072);
        #define COLL(v, e) if ((skey(v) >> 20) >= bt) { \
            int pos = atomicAdd(&s_cnt, 1); \
            if (pos < BUFCAP) { s_bufv[pos] = (v); s_bufi[pos] = (e); } }
        COLL(r0.x, b0 + 0) COLL(r0.y, b0 + 1) COLL(r0.z, b0 + 2) COLL(r0.w, b0 + 3)
        COLL(r1.x, b1 + 0) COLL(r1.y, b1 + 1) COLL(r1.z, b1 + 2) COLL(r1.w, b1 + 3)
        COLL(r2.x, b2 + 0) COLL(r2.y, b2 + 1) COLL(r2.z, b2 + 2) COLL(r2.w, b2 + 3)
        if (has3) { COLL(r3.x, b3 + 0) COLL(r3.y, b3 + 1) COLL(r3.z, b3 + 2) COLL(r3.w, b3 + 3) }
        #undef COLL
    }
    __syncthreads();
    int C = s_cnt; if (C > BUFCAP) C = BUFCAP;

    // ---- Exact top-60 by rank counting (desc value, tie: lower index first) ----
    for (int j = tid; j < C; j += BLOCK) {
        const float vj = s_bufv[j];
        const int   ij = s_bufi[j];
        int r = 0;
        for (int k = 0; k < C; ++k) {
            const float vk = s_bufv[k];
            const int   ik = s_bufi[k];
            r += (int)((vk > vj) || (vk == vj && ik < ij));
        }
        if (r < TOPK) { s_topv[r] = vj; s_topi[r] = ij; }
    }
    __syncthreads();

    // ---- Decode boxes for the 60 finalists ----
    if (tid < TOPK) {
        const float v = s_topv[tid];
        const int   a = s_topi[tid];
        const float score = 1.0f / (1.0f + expf(-v));
        const int z  = a / (DD * DD);
        const int y  = (a / DD) % DD;
        const int xg = a % DD;
        const size_t base3 = (size_t)b * 3 * AA;
        const float o0 = off[base3 + 0 * AA + a];
        const float o1 = off[base3 + 1 * AA + a];
        const float o2 = off[base3 + 2 * AA + a];
        const float s0 = shp[base3 + 0 * AA + a];
        const float s1 = shp[base3 + 1 * AA + a];
        const float s2 = shp[base3 + 2 * AA + a];
        const float cz = ((float)z  + o0) * 4.0f;
        const float cy = ((float)y  + o1) * 4.0f;
        const float cx = ((float)xg + o2) * 4.0f;
        const float ez = 2.0f * s0, ey = 2.0f * s1, ex = 2.0f * s2;
        // mirror reference fp op order exactly
        s_lo[0][tid] = cz - ez * 0.5f;  s_hi[0][tid] = cz + ez * 0.5f;
        s_lo[1][tid] = cy - ey * 0.5f;  s_hi[1][tid] = cy + ey * 0.5f;
        s_lo[2][tid] = cx - ex * 0.5f;  s_hi[2][tid] = cx + ex * 0.5f;
        s_vol[tid]   = (ez * ey) * ex;
        s_det[tid][0] = 1.0f;  s_det[tid][1] = score;
        s_det[tid][2] = cz;    s_det[tid][3] = cy;   s_det[tid][4] = cx;
        s_det[tid][5] = ez;    s_det[tid][6] = ey;   s_det[tid][7] = ex;
    }
    __syncthreads();

    // ---- Parallel IoU suppression masks (3600 pairs) + candidate mask ----
    if (tid == 0) {
        unsigned long long cm = 0ull; int nv = 0;
        for (int i = 0; i < TOPK; ++i) {
            if (s_det[i][1] > THRESH) {
                if (nv < NMS_TOPK) cm |= (1ull << i);
                ++nv;
            }
        }
        s_candmask = cm;
    }
    for (int p = tid; p < TOPK * TOPK; p += BLOCK) {
        const int i = p / TOPK, j = p - i * TOPK;
        if (i != j) {
            const float tz = fmaxf(fminf(s_hi[0][i], s_hi[0][j]) - fmaxf(s_lo[0][i], s_lo[0][j]), 0.0f);
            const float ty = fmaxf(fminf(s_hi[1][i], s_hi[1][j]) - fmaxf(s_lo[1][i], s_lo[1][j]), 0.0f);
            const float tx = fmaxf(fminf(s_hi[2][i], s_hi[2][j]) - fmaxf(s_lo[2][i], s_lo[2][j]), 0.0f);
            const float inter = (tz * ty) * tx;
            const float uni = (s_vol[i] + s_vol[j]) - inter;
            const float iou = inter / fmaxf(uni, 1e-8f);
            if (iou > NMS_THR) {
                if (j < 32) atomicOr(&s_mLo[i], 1u << j);
                else        atomicOr(&s_mHi[i], 1u << (j - 32));
            }
        }
    }
    __syncthreads();

    // ---- Serial greedy NMS (pure bit ops, thread 0) ----
    if (tid == 0) {
        unsigned long long supp = 0ull, kept = 0ull;
        const unsigned long long cm = s_candmask;
        for (int i = 0; i < TOPK; ++i) {
            const unsigned long long bit = 1ull << i;
            if ((cm & bit) && !(supp & bit)) {
                kept |= bit;
                supp |= ((unsigned long long)s_mHi[i] << 32) | s_mLo[i];
            }
        }
        s_keptmask = kept;
    }
    __syncthreads();

    // ---- Output ----
    const unsigned long long kept = s_keptmask;
    const int K = __popcll(kept);
    float* ob = out + (size_t)b * (TOPK * 8);
    if (tid < TOPK && ((kept >> tid) & 1ull)) {
        const int r = __popcll(kept & ((1ull << tid) - 1ull));
        float* row = ob + r * 8;
        #pragma unroll
        for (int q = 0; q < 8; ++q) row[q] = s_det[tid][q];
    }
    const int fill = (TOPK - K) * 8;
    for (int idx = tid; idx < fill; idx += BLOCK) ob[K * 8 + idx] = -1.0f;
}

extern "C" void kernel_launch(void* const* d_in, const int* in_sizes, int n_in,
                              void* d_out, int out_size, void* d_ws, size_t ws_size,
                              hipStream_t stream) {
    (void)n_in; (void)out_size; (void)d_ws; (void)ws_size;
    const float* cls = (const float*)d_in[0];
    const float* shp = (const float*)d_in[1];
    const float* off = (const float*)d_in[2];
    float* out = (float*)d_out;
    const int B = in_sizes[0] / AA;   // 256
    detpost<<<B, BLOCK, 0, stream>>>(cls, shp, off, out);
}